// Round 7
// baseline (1022.812 us; speedup 1.0000x reference)
//
#include <hip/hip_runtime.h>
#include <cstddef>
#include <cstdint>

#define N_NODES 10000
#define N_EDGES 160000
#define NWAVES  8192   // node_agg: 2048 blocks x 4 waves, fully resident

// ---- constants ----
#define RS8    0.35355339059327373f   // 1/sqrt(8)
#define RS32   0.17677669529663687f   // 1/sqrt(32)
#define RS96   0.10206207261596575f   // 1/sqrt(96)
#define RS128  0.08838834764831845f   // 1/sqrt(128)
#define RS3    0.5773502691896258f    // 1/sqrt(3)
#define SQ3_   1.7320508075688772f
#define SQ5_   2.23606797749979f
#define A_     0.18257418583505536f   // 1/sqrt(30)
#define B_     0.31622776601683794f   // 1/sqrt(10)
#define SILU_C_ 1.6765208f
#define CS_    0.3826834323650898f    // sin(pi/8)
#define CX_    0.9238795325112867f    // cos(pi/8)
#define QDEG   0.25f                  // 1/sqrt(16)

typedef __attribute__((ext_vector_type(8))) short bf16x8;
typedef __attribute__((ext_vector_type(4))) float f32x4;

__device__ inline float bf2f(unsigned v) {
  union { unsigned u; float f; } c; c.u = v << 16; return c.f;
}
__device__ inline unsigned short f2bf(float f) {
  union { float f; unsigned u; } c; c.f = f;
  unsigned r = c.u + 0x7fff + ((c.u >> 16) & 1);
  return (unsigned short)(r >> 16);
}
__device__ inline unsigned pack2bf(float a, float b) {
  return (unsigned)f2bf(a) | ((unsigned)f2bf(b) << 16);
}

// zero counts + build fc1p (fc1 64x320 f32 -> bf16 MFMA B-fragment order)
__global__ void k_init(int* __restrict__ counts, const float* __restrict__ fc1,
                       unsigned short* __restrict__ fc1p) {
  int i = blockIdx.x * blockDim.x + threadIdx.x;
  if (i < N_NODES) counts[i] = 0;
  if (i < 20480) {
    int j = i & 7, q = (i >> 3) & 3, n = (i >> 5) & 15, kq = (i >> 9) & 1, t = i >> 10;
    int k = kq * 32 + q * 8 + j;
    fc1p[i] = f2bf(fc1[k * 320 + t * 16 + n]);
  }
}

__global__ void k_hist(const int* __restrict__ edst, int* __restrict__ counts) {
  int e = blockIdx.x * blockDim.x + threadIdx.x;
  if (e < N_EDGES) atomicAdd(&counts[edst[e]], 1);
}

// exclusive scan of counts -> offs/cur; degree histogram + descending-degree
// exclusive scan -> dcur (single block).
__global__ __launch_bounds__(256) void k_scan(const int* __restrict__ counts,
                                              int* __restrict__ offs,
                                              int* __restrict__ cur,
                                              int* __restrict__ dcur) {
  __shared__ int ps[256];
  __shared__ int dbin[256];
  int t = threadIdx.x;
  dbin[t] = 0;
  int base = t * 40;
  int sum = 0;
  for (int i = 0; i < 40; ++i) {
    int idx = base + i;
    if (idx < N_NODES) sum += counts[idx];
  }
  ps[t] = sum;
  __syncthreads();
  for (int off = 1; off < 256; off <<= 1) {
    int v = (t >= off) ? ps[t - off] : 0;
    __syncthreads();
    ps[t] += v;
    __syncthreads();
  }
  int run = (t == 0) ? 0 : ps[t - 1];
  for (int i = 0; i < 40; ++i) {
    int idx = base + i;
    if (idx < N_NODES) {
      int c = counts[idx];
      offs[idx] = run; cur[idx] = run;
      run += c;
      atomicAdd(&dbin[c < 255 ? c : 255], 1);
    }
  }
  __syncthreads();
  int rb = 255 - t;
  int v = dbin[rb];
  __syncthreads();
  ps[t] = v;
  __syncthreads();
  for (int off = 1; off < 256; off <<= 1) {
    int u = (t >= off) ? ps[t - off] : 0;
    __syncthreads();
    ps[t] += u;
    __syncthreads();
  }
  dcur[rb] = ps[t] - v;
}

// edge scatter (sorted-by-dst) + node scatter (descending-degree order)
__global__ void k_scatter(const int* __restrict__ edst, int* __restrict__ cur,
                          int* __restrict__ sorted, const int* __restrict__ counts,
                          int* __restrict__ dcur, int* __restrict__ order) {
  int e = blockIdx.x * blockDim.x + threadIdx.x;
  if (e < N_EDGES) {
    int d = edst[e];
    int p = atomicAdd(&cur[d], 1);
    sorted[p] = e;
  }
  if (e < N_NODES) {
    int b = counts[e]; b = b < 255 ? b : 255;
    int p = atomicAdd(&dcur[b], 1);
    order[p] = e;
  }
}

// s[n][0:160], y[n][0:160]
__global__ void node_pre(const float* __restrict__ xin, const float* __restrict__ attr,
                         const float* __restrict__ sc_w0, const float* __restrict__ sc_w1,
                         const float* __restrict__ l1_w0, const float* __restrict__ l1_w1,
                         float* __restrict__ s, float* __restrict__ y) {
  int idx = blockIdx.x * blockDim.x + threadIdx.x;
  int n = idx / 160, c = idx - n * 160;
  const float* xr = xin + (size_t)n * 160;
  float a = attr[n];
  float sv, yv;
  if (c < 64) {
    float s_ = 0.f, y_ = 0.f;
    #pragma unroll 8
    for (int u = 0; u < 64; ++u) {
      float x = xr[u];
      s_ += x * sc_w0[u * 64 + c];
      y_ += x * l1_w0[u * 64 + c];
    }
    sv = s_ * a * 0.125f; yv = y_ * a * 0.125f;
  } else {
    int t = c - 64; int v = t / 3, i = t - v * 3;
    float s_ = 0.f, y_ = 0.f;
    #pragma unroll 8
    for (int u = 0; u < 32; ++u) {
      float x = xr[64 + u * 3 + i];
      s_ += x * sc_w1[u * 32 + v];
      y_ += x * l1_w1[u * 32 + v];
    }
    sv = s_ * a * RS32; yv = y_ * a * RS32;
  }
  s[idx] = sv; y[idx] = yv;
}

// MFMA bf16 radial GEMM over 64 SORTED edges per block. TRANSPOSED output:
// mfma(B,A) -> D[row=wcol][col=edge], so each lane stores 4 CONTIGUOUS bf16
// w-columns per tile as one 8B store. ed_s (stride 12, slot 9 = src id)
// assembled in LDS, written as float4s.
__global__ __launch_bounds__(256) void w_gemm(
    const float* __restrict__ ele, const float* __restrict__ fc0,
    const int* __restrict__ sorted, const int* __restrict__ esrc,
    const float* __restrict__ eattr, const unsigned short* __restrict__ fc1p,
    unsigned short* __restrict__ wout, float* __restrict__ ed_s) {
  __shared__ int sh_ids[64];
  __shared__ __align__(16) float sh_ele[64][8];
  __shared__ __align__(16) float sh_ed[64 * 12];
  __shared__ __align__(16) unsigned short sh_h[64 * 72];  // 72-stride pad
  int t = threadIdx.x;
  int eb = blockIdx.x * 64;

  if (t < 64) sh_ids[t] = sorted[eb + t];
  __syncthreads();
  if (t < 128) {
    int e = t >> 1, hh = t & 1;
    ((float4*)&sh_ele[e][0])[hh] = ((const float4*)(ele + (size_t)sh_ids[e] * 8))[hh];
  }
  for (int i = t; i < 576; i += 256) {
    int e = i / 9, k = i - e * 9;
    sh_ed[e * 12 + k] = eattr[(size_t)sh_ids[e] * 9 + k];
  }
  if (t < 64) {
    ((int*)sh_ed)[t * 12 + 9] = esrc[sh_ids[t]];
    sh_ed[t * 12 + 10] = 0.f; sh_ed[t * 12 + 11] = 0.f;
  }
  __syncthreads();
  // write ed_s coalesced (192 float4s)
  if (t < 192)
    ((float4*)(ed_s + (size_t)eb * 12))[t] = ((const float4*)sh_ed)[t];
  // h = silu(ele@fc0/sqrt8)*SILU_C -> bf16, A-layout [edge][k], stride 72
  #pragma unroll
  for (int ii = 0; ii < 16; ++ii) {
    int idx = t + ii * 256;
    int e = idx >> 6, k = idx & 63;
    float acc = 0.f;
    #pragma unroll
    for (int m = 0; m < 8; ++m) acc += sh_ele[e][m] * fc0[m * 64 + k];
    acc *= RS8;
    float hv = SILU_C_ * acc / (1.f + __expf(-acc));
    sh_h[e * 72 + k] = f2bf(hv);
  }
  __syncthreads();

  int wv = t >> 6, lane = t & 63;
  int m0 = wv * 16;
  int mrow = lane & 15, quad = lane >> 4;
  // h-frag (identical lane mapping serves as the B operand after swap)
  bf16x8 a0 = *(const bf16x8*)(sh_h + (m0 + mrow) * 72 + quad * 8);
  bf16x8 a1 = *(const bf16x8*)(sh_h + (m0 + mrow) * 72 + 32 + quad * 8);
  // per-lane output base: edge row = eb+m0+mrow, col chunk = quad*4
  unsigned short* wrow = wout + (size_t)(eb + m0 + mrow) * 320 + quad * 4;
  #pragma unroll 4
  for (int t20 = 0; t20 < 20; ++t20) {
    f32x4 acc = {0.f, 0.f, 0.f, 0.f};
    bf16x8 b0 = *(const bf16x8*)(fc1p + ((size_t)((t20 * 2 + 0) * 16 + mrow) * 4 + quad) * 8);
    bf16x8 b1 = *(const bf16x8*)(fc1p + ((size_t)((t20 * 2 + 1) * 16 + mrow) * 4 + quad) * 8);
    // SWAPPED operands: D = fc1^T-tile @ h^T-tile = w^T tile
    acc = __builtin_amdgcn_mfma_f32_16x16x32_bf16(b0, a0, acc, 0, 0, 0);
    acc = __builtin_amdgcn_mfma_f32_16x16x32_bf16(b1, a1, acc, 0, 0, 0);
    uint2 pk;
    pk.x = pack2bf(acc[0] * 0.125f, acc[1] * 0.125f);
    pk.y = pack2bf(acc[2] * 0.125f, acc[3] * 0.125f);
    *(uint2*)(wrow + t20 * 16) = pk;
  }
}

__device__ inline float lin2_col(const float* __restrict__ sm,
                                 const float* __restrict__ w0,
                                 const float* __restrict__ w1,
                                 const float* __restrict__ w2,
                                 const float* __restrict__ srow,
                                 float a, int oc) {
  if (oc < 64) {
    float o = 0.f;
    #pragma unroll 8
    for (int u = 0; u < 96; ++u) o += sm[u] * w0[u * 64 + oc];
    return CS_ * srow[oc] + CX_ * (o * a * RS96);
  } else if (oc < 160) {
    int t = oc - 64, v = t / 3, i = t - v * 3;
    float o = 0.f;
    #pragma unroll 8
    for (int u = 0; u < 128; ++u) o += sm[96 + u * 3 + i] * w1[u * 32 + v];
    return CS_ * srow[oc] + CX_ * (o * a * RS128);
  } else {
    int t = oc - 160, v = t / 5, k = t - v * 5;
    float o = 0.f;
    #pragma unroll 8
    for (int u = 0; u < 96; ++u) o += sm[480 + u * 5 + k] * w2[u * 32 + v];
    return o * a * RS96;
  }
}

// PERSISTENT: 2048 blocks x 4 waves, fully resident; each wave grid-strides
// over degree-ordered nodes. u-major lane mapping, direct global->lane loads,
// depth-2 register prefetch. No block barriers.
#define WREG 960
__global__ __launch_bounds__(256, 8) void node_agg(
    const float* __restrict__ y, const float* __restrict__ s,
    const float* __restrict__ attr, const float* __restrict__ ed_s,
    const unsigned short* __restrict__ wbuf,
    const int* __restrict__ offs, const int* __restrict__ counts,
    const int* __restrict__ order,
    const float* __restrict__ w0, const float* __restrict__ w1,
    const float* __restrict__ w2, float* __restrict__ out) {
  __shared__ __align__(16) float smem[4 * WREG];
  int tid = threadIdx.x, wid = tid >> 6, lane = tid & 63, l31 = lane & 31;
  float* R = smem + wid * WREG;
  int gw = blockIdx.x * 4 + wid;

#define ISSUE(S, gg, sv)                                                       \
  {                                                                            \
    const float* yb = y + (size_t)(sv) * 160;                                  \
    Y##S = yb[lane];                                                           \
    X0##S = yb[64 + 3 * l31]; X1##S = yb[65 + 3 * l31]; X2##S = yb[66 + 3 * l31]; \
    const unsigned short* wb = wbuf + (size_t)(gg) * 320;                      \
    wA##S = wb[lane]; wB##S = wb[64 + lane]; wC##S = wb[128 + lane];           \
    wD##S = wb[192 + l31]; wE##S = wb[224 + l31];                              \
    wF##S = wb[256 + l31]; wG##S = wb[288 + l31];                              \
    const float4* ep = (const float4*)(ed_s + (size_t)(gg) * 12);              \
    P0##S = ep[0]; P1##S = ep[1]; P2##S = ep[2];                               \
  }

#define COMPUTE(S)                                                             \
  {                                                                            \
    float e0 = P0##S.x, ey = P0##S.y, ez = P0##S.z, ex = P0##S.w;              \
    float q0 = P1##S.x, q1 = P1##S.y, q2 = P1##S.z, q3 = P1##S.w;              \
    float q4 = P2##S.x;                                                        \
    float Yv = Y##S, x0 = X0##S, x1 = X1##S, x2 = X2##S;                       \
    float vA = bf2f(wA##S), vB = bf2f(wB##S), vC = bf2f(wC##S);                \
    float vD = bf2f(wD##S), vE = bf2f(wE##S), vF = bf2f(wF##S), vG = bf2f(wG##S); \
    aK0 += Yv * e0 * vA;                                                       \
    float tB = Yv * vB; aK2x += tB * ey; aK2y += tB * ez; aK2z += tB * ex;     \
    float tC = Yv * vC;                                                        \
    aK5a += tC * q0; aK5b += tC * q1; aK5c += tC * q2;                         \
    aK5d += tC * q3; aK5e += tC * q4;                                          \
    float t1 = x0 * ey + x1 * ez + x2 * ex; aK1 += (RS3 * vE) * t1;            \
    float s3 = e0 * vD; aK3x += x0 * s3; aK3y += x1 * s3; aK3z += x2 * s3;     \
    float s4 = SQ3_ * vG;                                                      \
    aK4x += s4 * (B_ * (x2 * q0 + x1 * q1 - x0 * q4) - A_ * x0 * q2);          \
    aK4y += s4 * (B_ * (x0 * q1 + x2 * q3) + 2.f * A_ * x1 * q2);              \
    aK4z += s4 * (B_ * (x0 * q0 + x1 * q3 + x2 * q4) - A_ * x2 * q2);          \
    float s6 = SQ5_ * vF;                                                      \
    aK6a += s6 * (-B_ * (x0 * ex + x2 * ey));                                  \
    aK6b += s6 * (-B_ * (x0 * ez + x1 * ey));                                  \
    aK6c += s6 * ( A_ * (x0 * ey + x2 * ex - 2.f * x1 * ez));                  \
    aK6d += s6 * (-B_ * (x1 * ex + x2 * ez));                                  \
    aK6e += s6 * ( B_ * (x0 * ey - x2 * ex));                                  \
  }
#define SRC_OF(gg) (((const int*)ed_s)[(size_t)(gg) * 12 + 9])
#define LWAIT __asm__ volatile("s_waitcnt lgkmcnt(0)" ::: "memory")

  for (int ni = gw; ni < N_NODES; ni += NWAVES) {
    int n = order[ni];
    int beg = offs[n], cnt = counts[n];

    float aK0 = 0.f, aK2x = 0.f, aK2y = 0.f, aK2z = 0.f;
    float aK5a = 0.f, aK5b = 0.f, aK5c = 0.f, aK5d = 0.f, aK5e = 0.f;
    float aK1 = 0.f, aK3x = 0.f, aK3y = 0.f, aK3z = 0.f;
    float aK4x = 0.f, aK4y = 0.f, aK4z = 0.f;
    float aK6a = 0.f, aK6b = 0.f, aK6c = 0.f, aK6d = 0.f, aK6e = 0.f;

    float Ya, X0a, X1a, X2a, Yb, X0b, X1b, X2b;
    unsigned wAa, wBa, wCa, wDa, wEa, wFa, wGa;
    unsigned wAb, wBb, wCb, wDb, wEb, wFb, wGb;
    float4 P0a, P1a, P2a, P0b, P1b, P2b;

    if (cnt > 0) {
      int sA = SRC_OF(beg);
      ISSUE(a, beg, sA);
      int s_next = (cnt > 1) ? SRC_OF(beg + 1) : 0;
      int i = 0;
      while (true) {
        int s_next2 = (i + 2 < cnt) ? SRC_OF(beg + i + 2) : 0;
        if (i + 1 < cnt) ISSUE(b, beg + i + 1, s_next);
        COMPUTE(a);
        ++i; if (i >= cnt) break;
        s_next = s_next2;
        s_next2 = (i + 2 < cnt) ? SRC_OF(beg + i + 2) : 0;
        if (i + 1 < cnt) ISSUE(a, beg + i + 1, s_next);
        COMPUTE(b);
        ++i; if (i >= cnt) break;
        s_next = s_next2;
      }
    }

    // epilogue: distributed accs -> wave-private m (LDS) -> lin2 + combine
    LWAIT;  // previous node's lin2 LDS reads drained before overwrite
    R[lane]            = aK0  * QDEG;
    R[96 + 3 * lane]   = aK2x * QDEG;
    R[97 + 3 * lane]   = aK2y * QDEG;
    R[98 + 3 * lane]   = aK2z * QDEG;
    R[480 + 5 * lane]  = aK5a * QDEG;
    R[481 + 5 * lane]  = aK5b * QDEG;
    R[482 + 5 * lane]  = aK5c * QDEG;
    R[483 + 5 * lane]  = aK5d * QDEG;
    R[484 + 5 * lane]  = aK5e * QDEG;
    if (lane < 32) {
      R[64 + lane]       = aK1  * QDEG;
      R[288 + 3 * lane]  = aK3x * QDEG;
      R[289 + 3 * lane]  = aK3y * QDEG;
      R[290 + 3 * lane]  = aK3z * QDEG;
      R[384 + 3 * lane]  = aK4x * QDEG;
      R[385 + 3 * lane]  = aK4y * QDEG;
      R[386 + 3 * lane]  = aK4z * QDEG;
      R[800 + 5 * lane]  = aK6a * QDEG;
      R[801 + 5 * lane]  = aK6b * QDEG;
      R[802 + 5 * lane]  = aK6c * QDEG;
      R[803 + 5 * lane]  = aK6d * QDEG;
      R[804 + 5 * lane]  = aK6e * QDEG;
    }
    LWAIT;
    float a = attr[n];
    const float* srow = s + (size_t)n * 160;
    float* orow = out + (size_t)n * 320;
    #pragma unroll
    for (int jo = 0; jo < 5; ++jo) {
      int oc = lane + 64 * jo;
      orow[oc] = lin2_col(R, w0, w1, w2, srow, a, oc);
    }
  }
#undef ISSUE
#undef COMPUTE
#undef SRC_OF
#undef LWAIT
}

extern "C" void kernel_launch(void* const* d_in, const int* in_sizes, int n_in,
                              void* d_out, int out_size, void* d_ws, size_t ws_size,
                              hipStream_t stream) {
  const float* node_input = (const float*)d_in[0];
  const float* node_attr  = (const float*)d_in[1];
  const int*   edge_src   = (const int*)d_in[2];
  const int*   edge_dst   = (const int*)d_in[3];
  const float* edge_attr  = (const float*)d_in[4];
  const float* ele        = (const float*)d_in[5];
  const float* sc_w0      = (const float*)d_in[6];
  const float* sc_w1      = (const float*)d_in[7];
  const float* l1_w0      = (const float*)d_in[8];
  const float* l1_w1      = (const float*)d_in[9];
  const float* fc_w0      = (const float*)d_in[10];
  const float* fc_w1      = (const float*)d_in[11];
  const float* l2_w0      = (const float*)d_in[12];
  const float* l2_w1      = (const float*)d_in[13];
  const float* l2_w2      = (const float*)d_in[14];
  float* out = (float*)d_out;

  char* base = (char*)d_ws;
  float* y              = (float*)(base);                       // 6.40 MB
  float* s              = (float*)(base + 6400000);             // 6.40 MB
  unsigned short* wbuf  = (unsigned short*)(base + 12800000);   // 102.4 MB
  float* ed_s           = (float*)(base + 115200000);           // 7.68 MB (SH + src)
  int* counts           = (int*)(base + 122880000);             // 40 KB
  int* offs             = (int*)(base + 122920000);
  int* cur              = (int*)(base + 122960000);
  int* sorted           = (int*)(base + 123000000);             // 0.64 MB
  unsigned short* fc1p  = (unsigned short*)(base + 123640000);  // 40 KB
  int* dcur             = (int*)(base + 123680960);             // 1 KB
  int* order            = (int*)(base + 123682048);             // 40 KB

  hipLaunchKernelGGL(k_init, dim3(80), dim3(256), 0, stream, counts, fc_w1, fc1p);
  hipLaunchKernelGGL(k_hist, dim3((N_EDGES + 255) / 256), dim3(256), 0, stream,
                     edge_dst, counts);
  hipLaunchKernelGGL(k_scan, dim3(1), dim3(256), 0, stream, counts, offs, cur, dcur);
  hipLaunchKernelGGL(k_scatter, dim3((N_EDGES + 255) / 256), dim3(256), 0, stream,
                     edge_dst, cur, sorted, counts, dcur, order);
  hipLaunchKernelGGL(node_pre, dim3(N_NODES * 160 / 256), dim3(256), 0, stream,
                     node_input, node_attr, sc_w0, sc_w1, l1_w0, l1_w1, s, y);
  hipLaunchKernelGGL(w_gemm, dim3(N_EDGES / 64), dim3(256), 0, stream,
                     ele, fc_w0, sorted, edge_src, edge_attr, fc1p, wbuf, ed_s);
  hipLaunchKernelGGL(node_agg, dim3(NWAVES / 4), dim3(256), 0, stream,
                     y, s, node_attr, ed_s, wbuf,
                     offs, counts, order, l2_w0, l2_w1, l2_w2, out);
}

// Round 8
// 374.067 us; speedup vs baseline: 2.7343x; 2.7343x over previous
//
#include <hip/hip_runtime.h>
#include <cstddef>
#include <cstdint>

#define N_NODES 10000
#define N_EDGES 160000
#define NWAVES  8192   // node_agg: 2048 blocks x 4 waves, persistent grid-stride

// ---- constants ----
#define RS8    0.35355339059327373f   // 1/sqrt(8)
#define RS32   0.17677669529663687f   // 1/sqrt(32)
#define RS96   0.10206207261596575f   // 1/sqrt(96)
#define RS128  0.08838834764831845f   // 1/sqrt(128)
#define RS3    0.5773502691896258f    // 1/sqrt(3)
#define SQ3_   1.7320508075688772f
#define SQ5_   2.23606797749979f
#define A_     0.18257418583505536f   // 1/sqrt(30)
#define B_     0.31622776601683794f   // 1/sqrt(10)
#define SILU_C_ 1.6765208f
#define CS_    0.3826834323650898f    // sin(pi/8)
#define CX_    0.9238795325112867f    // cos(pi/8)
#define QDEG   0.25f                  // 1/sqrt(16)

typedef __attribute__((ext_vector_type(8))) short bf16x8;
typedef __attribute__((ext_vector_type(4))) float f32x4;

__device__ inline float bf2f(unsigned v) {
  union { unsigned u; float f; } c; c.u = v << 16; return c.f;
}
__device__ inline unsigned short f2bf(float f) {
  union { float f; unsigned u; } c; c.f = f;
  unsigned r = c.u + 0x7fff + ((c.u >> 16) & 1);
  return (unsigned short)(r >> 16);
}
__device__ inline unsigned pack2bf(float a, float b) {
  return (unsigned)f2bf(a) | ((unsigned)f2bf(b) << 16);
}

// zero counts + build fc1p (fc1 64x320 f32 -> bf16 MFMA B-fragment order)
__global__ void k_init(int* __restrict__ counts, const float* __restrict__ fc1,
                       unsigned short* __restrict__ fc1p) {
  int i = blockIdx.x * blockDim.x + threadIdx.x;
  if (i < N_NODES) counts[i] = 0;
  if (i < 20480) {
    int j = i & 7, q = (i >> 3) & 3, n = (i >> 5) & 15, kq = (i >> 9) & 1, t = i >> 10;
    int k = kq * 32 + q * 8 + j;
    fc1p[i] = f2bf(fc1[k * 320 + t * 16 + n]);
  }
}

__global__ void k_hist(const int* __restrict__ edst, int* __restrict__ counts) {
  int e = blockIdx.x * blockDim.x + threadIdx.x;
  if (e < N_EDGES) atomicAdd(&counts[edst[e]], 1);
}

// exclusive scan of counts -> offs/cur; degree histogram + descending-degree
// exclusive scan -> dcur (single block).
__global__ __launch_bounds__(256) void k_scan(const int* __restrict__ counts,
                                              int* __restrict__ offs,
                                              int* __restrict__ cur,
                                              int* __restrict__ dcur) {
  __shared__ int ps[256];
  __shared__ int dbin[256];
  int t = threadIdx.x;
  dbin[t] = 0;
  int base = t * 40;
  int sum = 0;
  for (int i = 0; i < 40; ++i) {
    int idx = base + i;
    if (idx < N_NODES) sum += counts[idx];
  }
  ps[t] = sum;
  __syncthreads();
  for (int off = 1; off < 256; off <<= 1) {
    int v = (t >= off) ? ps[t - off] : 0;
    __syncthreads();
    ps[t] += v;
    __syncthreads();
  }
  int run = (t == 0) ? 0 : ps[t - 1];
  for (int i = 0; i < 40; ++i) {
    int idx = base + i;
    if (idx < N_NODES) {
      int c = counts[idx];
      offs[idx] = run; cur[idx] = run;
      run += c;
      atomicAdd(&dbin[c < 255 ? c : 255], 1);
    }
  }
  __syncthreads();
  int rb = 255 - t;
  int v = dbin[rb];
  __syncthreads();
  ps[t] = v;
  __syncthreads();
  for (int off = 1; off < 256; off <<= 1) {
    int u = (t >= off) ? ps[t - off] : 0;
    __syncthreads();
    ps[t] += u;
    __syncthreads();
  }
  dcur[rb] = ps[t] - v;
}

// edge scatter (sorted-by-dst) + node scatter (descending-degree order)
__global__ void k_scatter(const int* __restrict__ edst, int* __restrict__ cur,
                          int* __restrict__ sorted, const int* __restrict__ counts,
                          int* __restrict__ dcur, int* __restrict__ order) {
  int e = blockIdx.x * blockDim.x + threadIdx.x;
  if (e < N_EDGES) {
    int d = edst[e];
    int p = atomicAdd(&cur[d], 1);
    sorted[p] = e;
  }
  if (e < N_NODES) {
    int b = counts[e]; b = b < 255 ? b : 255;
    int p = atomicAdd(&dcur[b], 1);
    order[p] = e;
  }
}

// s[n][0:160], y[n][0:160]
__global__ void node_pre(const float* __restrict__ xin, const float* __restrict__ attr,
                         const float* __restrict__ sc_w0, const float* __restrict__ sc_w1,
                         const float* __restrict__ l1_w0, const float* __restrict__ l1_w1,
                         float* __restrict__ s, float* __restrict__ y) {
  int idx = blockIdx.x * blockDim.x + threadIdx.x;
  int n = idx / 160, c = idx - n * 160;
  const float* xr = xin + (size_t)n * 160;
  float a = attr[n];
  float sv, yv;
  if (c < 64) {
    float s_ = 0.f, y_ = 0.f;
    #pragma unroll 8
    for (int u = 0; u < 64; ++u) {
      float x = xr[u];
      s_ += x * sc_w0[u * 64 + c];
      y_ += x * l1_w0[u * 64 + c];
    }
    sv = s_ * a * 0.125f; yv = y_ * a * 0.125f;
  } else {
    int t = c - 64; int v = t / 3, i = t - v * 3;
    float s_ = 0.f, y_ = 0.f;
    #pragma unroll 8
    for (int u = 0; u < 32; ++u) {
      float x = xr[64 + u * 3 + i];
      s_ += x * sc_w1[u * 32 + v];
      y_ += x * l1_w1[u * 32 + v];
    }
    sv = s_ * a * RS32; yv = y_ * a * RS32;
  }
  s[idx] = sv; y[idx] = yv;
}

// MFMA bf16 radial GEMM over 64 SORTED edges per block. TRANSPOSED output:
// mfma(B,A) -> D[row=wcol][col=edge], so each lane stores 4 CONTIGUOUS bf16
// w-columns per tile as one 8B store. ed_s (stride 12, slot 9 = src id)
// assembled in LDS, written as float4s.
__global__ __launch_bounds__(256) void w_gemm(
    const float* __restrict__ ele, const float* __restrict__ fc0,
    const int* __restrict__ sorted, const int* __restrict__ esrc,
    const float* __restrict__ eattr, const unsigned short* __restrict__ fc1p,
    unsigned short* __restrict__ wout, float* __restrict__ ed_s) {
  __shared__ int sh_ids[64];
  __shared__ __align__(16) float sh_ele[64][8];
  __shared__ __align__(16) float sh_ed[64 * 12];
  __shared__ __align__(16) unsigned short sh_h[64 * 72];  // 72-stride pad
  int t = threadIdx.x;
  int eb = blockIdx.x * 64;

  if (t < 64) sh_ids[t] = sorted[eb + t];
  __syncthreads();
  if (t < 128) {
    int e = t >> 1, hh = t & 1;
    ((float4*)&sh_ele[e][0])[hh] = ((const float4*)(ele + (size_t)sh_ids[e] * 8))[hh];
  }
  for (int i = t; i < 576; i += 256) {
    int e = i / 9, k = i - e * 9;
    sh_ed[e * 12 + k] = eattr[(size_t)sh_ids[e] * 9 + k];
  }
  if (t < 64) {
    ((int*)sh_ed)[t * 12 + 9] = esrc[sh_ids[t]];
    sh_ed[t * 12 + 10] = 0.f; sh_ed[t * 12 + 11] = 0.f;
  }
  __syncthreads();
  // write ed_s coalesced (192 float4s)
  if (t < 192)
    ((float4*)(ed_s + (size_t)eb * 12))[t] = ((const float4*)sh_ed)[t];
  // h = silu(ele@fc0/sqrt8)*SILU_C -> bf16, A-layout [edge][k], stride 72
  #pragma unroll
  for (int ii = 0; ii < 16; ++ii) {
    int idx = t + ii * 256;
    int e = idx >> 6, k = idx & 63;
    float acc = 0.f;
    #pragma unroll
    for (int m = 0; m < 8; ++m) acc += sh_ele[e][m] * fc0[m * 64 + k];
    acc *= RS8;
    float hv = SILU_C_ * acc / (1.f + __expf(-acc));
    sh_h[e * 72 + k] = f2bf(hv);
  }
  __syncthreads();

  int wv = t >> 6, lane = t & 63;
  int m0 = wv * 16;
  int mrow = lane & 15, quad = lane >> 4;
  // h-frag (identical lane mapping serves as the B operand after swap)
  bf16x8 a0 = *(const bf16x8*)(sh_h + (m0 + mrow) * 72 + quad * 8);
  bf16x8 a1 = *(const bf16x8*)(sh_h + (m0 + mrow) * 72 + 32 + quad * 8);
  // per-lane output base: edge row = eb+m0+mrow, col chunk = quad*4
  unsigned short* wrow = wout + (size_t)(eb + m0 + mrow) * 320 + quad * 4;
  #pragma unroll 4
  for (int t20 = 0; t20 < 20; ++t20) {
    f32x4 acc = {0.f, 0.f, 0.f, 0.f};
    bf16x8 b0 = *(const bf16x8*)(fc1p + ((size_t)((t20 * 2 + 0) * 16 + mrow) * 4 + quad) * 8);
    bf16x8 b1 = *(const bf16x8*)(fc1p + ((size_t)((t20 * 2 + 1) * 16 + mrow) * 4 + quad) * 8);
    // SWAPPED operands: D = fc1^T-tile @ h^T-tile = w^T tile
    acc = __builtin_amdgcn_mfma_f32_16x16x32_bf16(b0, a0, acc, 0, 0, 0);
    acc = __builtin_amdgcn_mfma_f32_16x16x32_bf16(b1, a1, acc, 0, 0, 0);
    uint2 pk;
    pk.x = pack2bf(acc[0] * 0.125f, acc[1] * 0.125f);
    pk.y = pack2bf(acc[2] * 0.125f, acc[3] * 0.125f);
    *(uint2*)(wrow + t20 * 16) = pk;
  }
}

__device__ inline float lin2_col(const float* __restrict__ sm,
                                 const float* __restrict__ w0,
                                 const float* __restrict__ w1,
                                 const float* __restrict__ w2,
                                 const float* __restrict__ srow,
                                 float a, int oc) {
  if (oc < 64) {
    float o = 0.f;
    #pragma unroll 8
    for (int u = 0; u < 96; ++u) o += sm[u] * w0[u * 64 + oc];
    return CS_ * srow[oc] + CX_ * (o * a * RS96);
  } else if (oc < 160) {
    int t = oc - 64, v = t / 3, i = t - v * 3;
    float o = 0.f;
    #pragma unroll 8
    for (int u = 0; u < 128; ++u) o += sm[96 + u * 3 + i] * w1[u * 32 + v];
    return CS_ * srow[oc] + CX_ * (o * a * RS128);
  } else {
    int t = oc - 160, v = t / 5, k = t - v * 5;
    float o = 0.f;
    #pragma unroll 8
    for (int u = 0; u < 96; ++u) o += sm[480 + u * 5 + k] * w2[u * 32 + v];
    return o * a * RS96;
  }
}

// PERSISTENT: 2048 blocks x 4 waves, grid-stride over degree-ordered nodes
// (wave k gets ~1 big node + ~1 small node — balanced, no drain tail).
// u-major lane mapping, direct global->lane loads, depth-2 register prefetch.
// NOTE: plain __launch_bounds__(256) — round 7's (256,8) capped VGPR at 32
// and spilled the prefetch state to scratch (FETCH 96->741 MB). 56 VGPR
// already fits 8 waves/EU; do NOT constrain the allocator.
#define WREG 960
__global__ __launch_bounds__(256) void node_agg(
    const float* __restrict__ y, const float* __restrict__ s,
    const float* __restrict__ attr, const float* __restrict__ ed_s,
    const unsigned short* __restrict__ wbuf,
    const int* __restrict__ offs, const int* __restrict__ counts,
    const int* __restrict__ order,
    const float* __restrict__ w0, const float* __restrict__ w1,
    const float* __restrict__ w2, float* __restrict__ out) {
  __shared__ __align__(16) float smem[4 * WREG];
  int tid = threadIdx.x, wid = tid >> 6, lane = tid & 63, l31 = lane & 31;
  float* R = smem + wid * WREG;
  int gw = blockIdx.x * 4 + wid;

#define ISSUE(S, gg, sv)                                                       \
  {                                                                            \
    const float* yb = y + (size_t)(sv) * 160;                                  \
    Y##S = yb[lane];                                                           \
    X0##S = yb[64 + 3 * l31]; X1##S = yb[65 + 3 * l31]; X2##S = yb[66 + 3 * l31]; \
    const unsigned short* wb = wbuf + (size_t)(gg) * 320;                      \
    wA##S = wb[lane]; wB##S = wb[64 + lane]; wC##S = wb[128 + lane];           \
    wD##S = wb[192 + l31]; wE##S = wb[224 + l31];                              \
    wF##S = wb[256 + l31]; wG##S = wb[288 + l31];                              \
    const float4* ep = (const float4*)(ed_s + (size_t)(gg) * 12);              \
    P0##S = ep[0]; P1##S = ep[1]; P2##S = ep[2];                               \
  }

#define COMPUTE(S)                                                             \
  {                                                                            \
    float e0 = P0##S.x, ey = P0##S.y, ez = P0##S.z, ex = P0##S.w;              \
    float q0 = P1##S.x, q1 = P1##S.y, q2 = P1##S.z, q3 = P1##S.w;              \
    float q4 = P2##S.x;                                                        \
    float Yv = Y##S, x0 = X0##S, x1 = X1##S, x2 = X2##S;                       \
    float vA = bf2f(wA##S), vB = bf2f(wB##S), vC = bf2f(wC##S);                \
    float vD = bf2f(wD##S), vE = bf2f(wE##S), vF = bf2f(wF##S), vG = bf2f(wG##S); \
    aK0 += Yv * e0 * vA;                                                       \
    float tB = Yv * vB; aK2x += tB * ey; aK2y += tB * ez; aK2z += tB * ex;     \
    float tC = Yv * vC;                                                        \
    aK5a += tC * q0; aK5b += tC * q1; aK5c += tC * q2;                         \
    aK5d += tC * q3; aK5e += tC * q4;                                          \
    float t1 = x0 * ey + x1 * ez + x2 * ex; aK1 += (RS3 * vE) * t1;            \
    float s3 = e0 * vD; aK3x += x0 * s3; aK3y += x1 * s3; aK3z += x2 * s3;     \
    float s4 = SQ3_ * vG;                                                      \
    aK4x += s4 * (B_ * (x2 * q0 + x1 * q1 - x0 * q4) - A_ * x0 * q2);          \
    aK4y += s4 * (B_ * (x0 * q1 + x2 * q3) + 2.f * A_ * x1 * q2);              \
    aK4z += s4 * (B_ * (x0 * q0 + x1 * q3 + x2 * q4) - A_ * x2 * q2);          \
    float s6 = SQ5_ * vF;                                                      \
    aK6a += s6 * (-B_ * (x0 * ex + x2 * ey));                                  \
    aK6b += s6 * (-B_ * (x0 * ez + x1 * ey));                                  \
    aK6c += s6 * ( A_ * (x0 * ey + x2 * ex - 2.f * x1 * ez));                  \
    aK6d += s6 * (-B_ * (x1 * ex + x2 * ez));                                  \
    aK6e += s6 * ( B_ * (x0 * ey - x2 * ex));                                  \
  }
#define SRC_OF(gg) (((const int*)ed_s)[(size_t)(gg) * 12 + 9])
#define LWAIT __asm__ volatile("s_waitcnt lgkmcnt(0)" ::: "memory")

  for (int ni = gw; ni < N_NODES; ni += NWAVES) {
    int n = order[ni];
    int beg = offs[n], cnt = counts[n];

    float aK0 = 0.f, aK2x = 0.f, aK2y = 0.f, aK2z = 0.f;
    float aK5a = 0.f, aK5b = 0.f, aK5c = 0.f, aK5d = 0.f, aK5e = 0.f;
    float aK1 = 0.f, aK3x = 0.f, aK3y = 0.f, aK3z = 0.f;
    float aK4x = 0.f, aK4y = 0.f, aK4z = 0.f;
    float aK6a = 0.f, aK6b = 0.f, aK6c = 0.f, aK6d = 0.f, aK6e = 0.f;

    float Ya, X0a, X1a, X2a, Yb, X0b, X1b, X2b;
    unsigned wAa, wBa, wCa, wDa, wEa, wFa, wGa;
    unsigned wAb, wBb, wCb, wDb, wEb, wFb, wGb;
    float4 P0a, P1a, P2a, P0b, P1b, P2b;

    if (cnt > 0) {
      int sA = SRC_OF(beg);
      ISSUE(a, beg, sA);
      int s_next = (cnt > 1) ? SRC_OF(beg + 1) : 0;
      int i = 0;
      while (true) {
        int s_next2 = (i + 2 < cnt) ? SRC_OF(beg + i + 2) : 0;
        if (i + 1 < cnt) ISSUE(b, beg + i + 1, s_next);
        COMPUTE(a);
        ++i; if (i >= cnt) break;
        s_next = s_next2;
        s_next2 = (i + 2 < cnt) ? SRC_OF(beg + i + 2) : 0;
        if (i + 1 < cnt) ISSUE(a, beg + i + 1, s_next);
        COMPUTE(b);
        ++i; if (i >= cnt) break;
        s_next = s_next2;
      }
    }

    // epilogue: distributed accs -> wave-private m (LDS) -> lin2 + combine
    LWAIT;  // previous node's lin2 LDS reads drained before overwrite
    R[lane]            = aK0  * QDEG;
    R[96 + 3 * lane]   = aK2x * QDEG;
    R[97 + 3 * lane]   = aK2y * QDEG;
    R[98 + 3 * lane]   = aK2z * QDEG;
    R[480 + 5 * lane]  = aK5a * QDEG;
    R[481 + 5 * lane]  = aK5b * QDEG;
    R[482 + 5 * lane]  = aK5c * QDEG;
    R[483 + 5 * lane]  = aK5d * QDEG;
    R[484 + 5 * lane]  = aK5e * QDEG;
    if (lane < 32) {
      R[64 + lane]       = aK1  * QDEG;
      R[288 + 3 * lane]  = aK3x * QDEG;
      R[289 + 3 * lane]  = aK3y * QDEG;
      R[290 + 3 * lane]  = aK3z * QDEG;
      R[384 + 3 * lane]  = aK4x * QDEG;
      R[385 + 3 * lane]  = aK4y * QDEG;
      R[386 + 3 * lane]  = aK4z * QDEG;
      R[800 + 5 * lane]  = aK6a * QDEG;
      R[801 + 5 * lane]  = aK6b * QDEG;
      R[802 + 5 * lane]  = aK6c * QDEG;
      R[803 + 5 * lane]  = aK6d * QDEG;
      R[804 + 5 * lane]  = aK6e * QDEG;
    }
    LWAIT;
    float a = attr[n];
    const float* srow = s + (size_t)n * 160;
    float* orow = out + (size_t)n * 320;
    #pragma unroll
    for (int jo = 0; jo < 5; ++jo) {
      int oc = lane + 64 * jo;
      orow[oc] = lin2_col(R, w0, w1, w2, srow, a, oc);
    }
  }
#undef ISSUE
#undef COMPUTE
#undef SRC_OF
#undef LWAIT
}

extern "C" void kernel_launch(void* const* d_in, const int* in_sizes, int n_in,
                              void* d_out, int out_size, void* d_ws, size_t ws_size,
                              hipStream_t stream) {
  const float* node_input = (const float*)d_in[0];
  const float* node_attr  = (const float*)d_in[1];
  const int*   edge_src   = (const int*)d_in[2];
  const int*   edge_dst   = (const int*)d_in[3];
  const float* edge_attr  = (const float*)d_in[4];
  const float* ele        = (const float*)d_in[5];
  const float* sc_w0      = (const float*)d_in[6];
  const float* sc_w1      = (const float*)d_in[7];
  const float* l1_w0      = (const float*)d_in[8];
  const float* l1_w1      = (const float*)d_in[9];
  const float* fc_w0      = (const float*)d_in[10];
  const float* fc_w1      = (const float*)d_in[11];
  const float* l2_w0      = (const float*)d_in[12];
  const float* l2_w1      = (const float*)d_in[13];
  const float* l2_w2      = (const float*)d_in[14];
  float* out = (float*)d_out;

  char* base = (char*)d_ws;
  float* y              = (float*)(base);                       // 6.40 MB
  float* s              = (float*)(base + 6400000);             // 6.40 MB
  unsigned short* wbuf  = (unsigned short*)(base + 12800000);   // 102.4 MB
  float* ed_s           = (float*)(base + 115200000);           // 7.68 MB (SH + src)
  int* counts           = (int*)(base + 122880000);             // 40 KB
  int* offs             = (int*)(base + 122920000);
  int* cur              = (int*)(base + 122960000);
  int* sorted           = (int*)(base + 123000000);             // 0.64 MB
  unsigned short* fc1p  = (unsigned short*)(base + 123640000);  // 40 KB
  int* dcur             = (int*)(base + 123680960);             // 1 KB
  int* order            = (int*)(base + 123682048);             // 40 KB

  hipLaunchKernelGGL(k_init, dim3(80), dim3(256), 0, stream, counts, fc_w1, fc1p);
  hipLaunchKernelGGL(k_hist, dim3((N_EDGES + 255) / 256), dim3(256), 0, stream,
                     edge_dst, counts);
  hipLaunchKernelGGL(k_scan, dim3(1), dim3(256), 0, stream, counts, offs, cur, dcur);
  hipLaunchKernelGGL(k_scatter, dim3((N_EDGES + 255) / 256), dim3(256), 0, stream,
                     edge_dst, cur, sorted, counts, dcur, order);
  hipLaunchKernelGGL(node_pre, dim3(N_NODES * 160 / 256), dim3(256), 0, stream,
                     node_input, node_attr, sc_w0, sc_w1, l1_w0, l1_w1, s, y);
  hipLaunchKernelGGL(w_gemm, dim3(N_EDGES / 64), dim3(256), 0, stream,
                     ele, fc_w0, sorted, edge_src, edge_attr, fc1p, wbuf, ed_s);
  hipLaunchKernelGGL(node_agg, dim3(NWAVES / 4), dim3(256), 0, stream,
                     y, s, node_attr, ed_s, wbuf,
                     offs, counts, order, l2_w0, l2_w1, l2_w2, out);
}